// Round 8
// baseline (1655.815 us; speedup 1.0000x reference)
//
#include <hip/hip_runtime.h>
#include <math.h>

#define HID 128
#define IN_DIM_C 500

// ---------------- small helpers ----------------
__device__ inline float eluf(float x) { return x > 0.f ? x : expm1f(x); }

// ---------------- scalar prep (softmaxes of alphas) ----------------
__global__ void prep_kernel(const float* __restrict__ na, const float* __restrict__ sc,
                            const float* __restrict__ la, float* __restrict__ s) {
    if (threadIdx.x != 0 || blockIdx.x != 0) return;
    for (int i = 0; i < 3; ++i) {
        float m = -1e30f;
        for (int k = 0; k < 5; ++k) m = fmaxf(m, na[i * 5 + k]);
        float d = 0.f;
        for (int k = 0; k < 5; ++k) d += expf(na[i * 5 + k] - m);
        for (int k = 0; k < 5; ++k) s[i * 5 + k] = expf(na[i * 5 + k] - m) / d;
    }
    for (int i = 0; i < 2; ++i) {
        float a = sc[i * 2], b = sc[i * 2 + 1];
        float m = fmaxf(a, b);
        float e0 = expf(a - m), e1 = expf(b - m);
        s[15 + i] = e1 / (e0 + e1);   // weight of "skip"
    }
    {
        float m = fmaxf(la[0], fmaxf(la[1], la[2]));
        float d = 0.f;
        for (int k = 0; k < 3; ++k) d += expf(la[k] - m);
        for (int k = 0; k < 3; ++k) s[17 + k] = expf(la[k] - m) / d;
    }
}

// va[(layer*2+which)*HID + j] = dot(gat_w[layer] row j, gat_a[layer][which])
__global__ void gatvec_kernel(const float* __restrict__ gat_w, const float* __restrict__ gat_a,
                              float* __restrict__ va) {
    int b = blockIdx.x;              // 0..5
    int layer = b >> 1, which = b & 1;
    int j = threadIdx.x;             // 0..127
    const float* W = gat_w + ((size_t)layer * HID + j) * HID;
    const float* a = gat_a + (size_t)layer * 2 * HID + which * HID;
    float s = 0.f;
    for (int k = 0; k < HID; k += 4) {
        float4 w = *(const float4*)&W[k];
        float4 av = *(const float4*)&a[k];
        s += w.x * av.x + w.y * av.y + w.z * av.z + w.w * av.w;
    }
    va[b * HID + j] = s;
}

// ---------------- graph preprocessing ----------------
__global__ void zero_int_kernel(int* __restrict__ p, int n) {
    int i = blockIdx.x * blockDim.x + threadIdx.x;
    if (i < n) p[i] = 0;
}

__global__ void degree_kernel(const int* __restrict__ dst, int* __restrict__ cnt, int E) {
    int e = blockIdx.x * blockDim.x + threadIdx.x;
    if (e < E) atomicAdd(&cnt[dst[e]], 1);
}

// Blocked single-block exclusive scan: thread t serially sums its chunk, one
// 1024-wide Hillis-Steele scan of the partials, then serial prefix write-back.
__global__ __launch_bounds__(1024) void exscan_kernel(const int* __restrict__ in,
                                                      int* __restrict__ out, int n) {
    __shared__ int buf[1024];
    int t = threadIdx.x;
    int chunk = (n + 1023) >> 10;
    int base = t * chunk;
    int end = base + chunk;
    if (end > n) end = n;
    int s = 0;
    for (int i = base; i < end; ++i) s += in[i];
    buf[t] = s;
    __syncthreads();
    int x = s;
    for (int o = 1; o < 1024; o <<= 1) {
        int add = (t >= o) ? buf[t - o] : 0;
        __syncthreads();
        x += add;
        buf[t] = x;
        __syncthreads();
    }
    int running = x - s;   // exclusive offset of this thread's chunk
    for (int i = base; i < end; ++i) {
        out[i] = running;
        running += in[i];
    }
}

__global__ void node_scalars_kernel(const int* __restrict__ cnt, float* __restrict__ rsqd,
                                    float* __restrict__ invcnt, float* __restrict__ invdeg, int n) {
    int i = blockIdx.x * blockDim.x + threadIdx.x;
    if (i >= n) return;
    float c = (float)cnt[i];
    rsqd[i] = rsqrtf(c + 1.f);
    invcnt[i] = 1.f / fmaxf(c, 1.f);
    invdeg[i] = 1.f / (c + 1.f);
}

__global__ void csr_fill_kernel(const int* __restrict__ src, const int* __restrict__ dst,
                                const int* __restrict__ offs, int* __restrict__ cursor,
                                int* __restrict__ csr_src, int E) {
    int e = blockIdx.x * blockDim.x + threadIdx.x;
    if (e >= E) return;
    int d = dst[e];
    int pos = offs[d] + atomicAdd(&cursor[d], 1);
    csr_src[pos] = src[e];
}

// ---------------- GEMM body: C = sum_j (scale_j * A_j) @ B_j (+bias)(+relu) --------
// A_j: n x K row-major, B_j: K x ncol row-major, C: n x ncol (ncol in {64,128}).
// In-place (C == A_j) is safe: each block reads only its own 64 rows of A before writing C.
__device__ __forceinline__ void gemm_body(
    const float* A1, const float* __restrict__ B1, const float* __restrict__ sc1p,
    const float* A2, const float* __restrict__ B2, const float* __restrict__ sc2p,
    const float* A3, const float* __restrict__ B3, const float* __restrict__ sc3p,
    const float* __restrict__ bias, float* C,
    int n, int K, int ncol, int act, int blk) {
    __shared__ float As[64][64];
    __shared__ float Bs[64][128];
    const int t = threadIdx.x;
    const int tx = t & 31, ty = t >> 5;
    const int rowbase = blk * 64;

    float4 acc[8];
#pragma unroll
    for (int r = 0; r < 8; ++r) { acc[r].x = 0.f; acc[r].y = 0.f; acc[r].z = 0.f; acc[r].w = 0.f; }

    const float* Aarr[3] = {A1, A2, A3};
    const float* Barr[3] = {B1, B2, B3};
    const float* scarr[3] = {sc1p, sc2p, sc3p};

    const int nf4 = ncol >> 2;

    for (int op = 0; op < 3; ++op) {
        const float* A = Aarr[op];
        if (!A) break;
        const float* B = Barr[op];
        float scv = scarr[op] ? *scarr[op] : 1.f;
        for (int k0 = 0; k0 < K; k0 += 64) {
            __syncthreads();
            // A chunk: 64 rows x 64 k
#pragma unroll
            for (int i = 0; i < 4; ++i) {
                int idx = t + i * 256;
                int row = idx >> 4, f4 = idx & 15;
                int grow = rowbase + row, gk = k0 + f4 * 4;
                float4 v; v.x = v.y = v.z = v.w = 0.f;
                if (grow < n) {
                    if (gk + 4 <= K) {
                        v = *(const float4*)&A[(size_t)grow * K + gk];
                    } else {
                        float tmp[4] = {0.f, 0.f, 0.f, 0.f};
                        for (int kk = 0; kk < 4; ++kk)
                            if (gk + kk < K) tmp[kk] = A[(size_t)grow * K + gk + kk];
                        v.x = tmp[0]; v.y = tmp[1]; v.z = tmp[2]; v.w = tmp[3];
                    }
                    v.x *= scv; v.y *= scv; v.z *= scv; v.w *= scv;
                }
                *(float4*)&As[row][f4 * 4] = v;
            }
            // B chunk: 64 k x ncol
            for (int idx = t; idx < 64 * nf4; idx += 256) {
                int kr = idx / nf4, c4 = idx % nf4;
                int gk = k0 + kr;
                float4 v; v.x = v.y = v.z = v.w = 0.f;
                if (gk < K) v = *(const float4*)&B[(size_t)gk * ncol + c4 * 4];
                *(float4*)&Bs[kr][c4 * 4] = v;
            }
            __syncthreads();
            if (tx * 4 < ncol) {
                for (int k = 0; k < 64; k += 4) {
                    float4 b0 = *(const float4*)&Bs[k][tx * 4];
                    float4 b1 = *(const float4*)&Bs[k + 1][tx * 4];
                    float4 b2 = *(const float4*)&Bs[k + 2][tx * 4];
                    float4 b3 = *(const float4*)&Bs[k + 3][tx * 4];
#pragma unroll
                    for (int r = 0; r < 8; ++r) {
                        float4 a = *(const float4*)&As[ty * 8 + r][k];
                        acc[r].x += a.x * b0.x + a.y * b1.x + a.z * b2.x + a.w * b3.x;
                        acc[r].y += a.x * b0.y + a.y * b1.y + a.z * b2.y + a.w * b3.y;
                        acc[r].z += a.x * b0.z + a.y * b1.z + a.z * b2.z + a.w * b3.z;
                        acc[r].w += a.x * b0.w + a.y * b1.w + a.z * b2.w + a.w * b3.w;
                    }
                }
            }
        }
    }

    if (tx * 4 < ncol) {
        float4 bv; bv.x = bv.y = bv.z = bv.w = 0.f;
        if (bias) bv = *(const float4*)&bias[tx * 4];
#pragma unroll
        for (int r = 0; r < 8; ++r) {
            int row = rowbase + ty * 8 + r;
            if (row >= n) break;
            float4 v = acc[r];
            v.x += bv.x; v.y += bv.y; v.z += bv.z; v.w += bv.w;
            if (act) {
                v.x = fmaxf(v.x, 0.f); v.y = fmaxf(v.y, 0.f);
                v.z = fmaxf(v.z, 0.f); v.w = fmaxf(v.w, 0.f);
            }
            *(float4*)&C[(size_t)row * ncol + tx * 4] = v;
        }
    }
}

__global__ __launch_bounds__(256) void gemm_f32(
    const float* A1, const float* __restrict__ B1, const float* __restrict__ sc1p,
    const float* A2, const float* __restrict__ B2, const float* __restrict__ sc2p,
    const float* A3, const float* __restrict__ B3, const float* __restrict__ sc3p,
    const float* __restrict__ bias, float* C,
    int n, int K, int ncol, int act) {
    gemm_body(A1, B1, sc1p, A2, B2, sc2p, A3, B3, sc3p, bias, C, n, K, ncol, act,
              blockIdx.x);
}

// Batched: the 5 independent per-layer GEMM products in one dispatch (blockIdx.y
// selects the product). Output buffers are pairwise distinct; h is read-only.
__global__ __launch_bounds__(256) void gemm_layer5(
    const float* __restrict__ h,
    float* AGa, const float* __restrict__ Wa,
    float* AGg, const float* __restrict__ Wg,
    float* TG,  const float* __restrict__ Wgin,
    float* AGs, const float* __restrict__ Wsm1, const float* __restrict__ Wsm2,
    float* AGm, const float* __restrict__ Wsx1, const float* __restrict__ Wsx2,
    int n) {
    const float *A1 = nullptr, *B1 = nullptr, *A2 = nullptr, *B2 = nullptr;
    float* C = nullptr;
    switch (blockIdx.y) {
        case 0: A1 = AGa; B1 = Wa;   C = AGa; break;                      // o_gat
        case 1: A1 = AGg; B1 = Wg;   C = AGg; break;                      // o_gcn
        case 2: A1 = TG;  B1 = Wgin; C = TG;  break;                      // o_gin
        case 3: A1 = h;   B1 = Wsm1; A2 = AGs; B2 = Wsm2; C = AGs; break; // o_sm
        default: A1 = h;  B1 = Wsx1; A2 = AGm; B2 = Wsx2; C = AGm; break; // o_sx
    }
    gemm_body(A1, B1, nullptr, A2, B2, nullptr, nullptr, nullptr, nullptr,
              nullptr, C, n, HID, HID, 0, blockIdx.x);
}

// ---------------- GAT logits: es = h @ va0, ed = h @ va1 (wave per node) ----------------
__global__ __launch_bounds__(256) void eproj_kernel(const float* __restrict__ h,
                                                    const float* __restrict__ va, int layer,
                                                    float* __restrict__ es, float* __restrict__ ed,
                                                    int n) {
    int wid = (blockIdx.x * 256 + threadIdx.x) >> 6;
    int lane = threadIdx.x & 63;
    if (wid >= n) return;
    float2 v = *(const float2*)&h[(size_t)wid * HID + lane * 2];
    float2 w0 = *(const float2*)&va[(layer * 2 + 0) * HID + lane * 2];
    float2 w1 = *(const float2*)&va[(layer * 2 + 1) * HID + lane * 2];
    float s0 = v.x * w0.x + v.y * w0.y;
    float s1 = v.x * w1.x + v.y * w1.y;
#pragma unroll
    for (int o = 32; o > 0; o >>= 1) {
        s0 += __shfl_xor(s0, o);
        s1 += __shfl_xor(s1, o);
    }
    if (lane == 0) { es[wid] = s0; ed[wid] = s1; }
}

// ---------------- fused per-node aggregation over h only (wave per node) ----------------
// GAT logit e = leaky_relu(es[src] + ed[dst], 0.2) computed on the fly (ed[dst] is
// wave-uniform). Emits GEMM-ready inputs (shared-B products pre-added):
//   sm_in  = invcnt[d] * seg_sum(h[src])                        (feeds @ Wsm2)
//   gcn_in = invdeg[d]*h[d] + rsqd[d]*seg_sum(rsqd[src]*h[src]) (feeds @ Wg)
//   gin_in = h[d] + seg_sum(h[src])                             (feeds @ Wgin)
//   ag_max = seg_max(h[src]) (0 if no edges)                    (feeds @ Wsx2)
//   ag_gat = seg_sum(softmax_coef * h[src])                     (feeds @ Wa)
__global__ __launch_bounds__(256) void aggregate_kernel(
    const float* __restrict__ h, const int* __restrict__ csr_src,
    const float* __restrict__ es, const float* __restrict__ ed,
    const int* __restrict__ offs, const int* __restrict__ cnt,
    const float* __restrict__ rsqd, const float* __restrict__ invcnt,
    const float* __restrict__ invdeg,
    float* __restrict__ sm_in, float* __restrict__ gcn_in, float* __restrict__ gin_in,
    float* __restrict__ ag_max, float* __restrict__ ag_gat, int n) {
    int wid = (blockIdx.x * 256 + threadIdx.x) >> 6;
    int lane = threadIdx.x & 63;
    if (wid >= n) return;
    int beg = offs[wid];
    int m = cnt[wid];
    int end = beg + m;
    float edv = ed[wid];

    // segment softmax scalars over incoming edges (logit recomputed per pass —
    // deterministic, so max/den/coef stay consistent)
    float emax = -INFINITY;
    for (int j = beg + lane; j < end; j += 64) {
        float v = es[csr_src[j]] + edv;
        float e = v > 0.f ? v : 0.2f * v;
        emax = fmaxf(emax, e);
    }
#pragma unroll
    for (int o = 32; o > 0; o >>= 1) emax = fmaxf(emax, __shfl_xor(emax, o));
    float den = 0.f;
    for (int j = beg + lane; j < end; j += 64) {
        float v = es[csr_src[j]] + edv;
        float e = v > 0.f ? v : 0.2f * v;
        den += __expf(e - emax);
    }
#pragma unroll
    for (int o = 32; o > 0; o >>= 1) den += __shfl_xor(den, o);
    float inv_den = 1.f / (den + 1e-16f);

    const float2* h2 = (const float2*)h;
    float sx = 0.f, sy = 0.f, gx = 0.f, gy = 0.f, ax = 0.f, ay = 0.f;
    float mxx = -INFINITY, mxy = -INFINITY;
#pragma unroll 4
    for (int j = beg; j < end; ++j) {
        int s = csr_src[j];
        float v = es[s] + edv;
        float e = v > 0.f ? v : 0.2f * v;
        float coef = __expf(e - emax) * inv_den;
        float rsd = rsqd[s];
        float2 hv = h2[(size_t)s * 64 + lane];
        sx += hv.x; sy += hv.y;
        gx += rsd * hv.x; gy += rsd * hv.y;
        mxx = fmaxf(mxx, hv.x); mxy = fmaxf(mxy, hv.y);
        ax += coef * hv.x; ay += coef * hv.y;
    }
    if (m == 0) { mxx = 0.f; mxy = 0.f; }

    size_t o2 = (size_t)wid * 64 + lane;
    float2 hd = h2[o2];                 // this node's own h row
    float icnt = invcnt[wid];
    float idg = invdeg[wid];
    float rsd_d = rsqd[wid];
    float2 r;
    r.x = icnt * sx;             r.y = icnt * sy;             ((float2*)sm_in)[o2] = r;
    r.x = idg * hd.x + rsd_d * gx; r.y = idg * hd.y + rsd_d * gy; ((float2*)gcn_in)[o2] = r;
    r.x = hd.x + sx;             r.y = hd.y + sy;             ((float2*)gin_in)[o2] = r;
    r.x = mxx;                   r.y = mxy;                   ((float2*)ag_max)[o2] = r;
    r.x = ax;                    r.y = ay;                    ((float2*)ag_gat)[o2] = r;
}

// ---------------- elementwise kernels ----------------
__global__ void combine_kernel(const float* __restrict__ o_gcn, const float* __restrict__ o_sm,
                               const float* __restrict__ o_sx, const float* __restrict__ o_gin,
                               const float* __restrict__ o_gat,
                               const float* __restrict__ scal, int layer,
                               float* __restrict__ xo, int n) {
    int i = blockIdx.x * blockDim.x + threadIdx.x;
    int tot = n * 32;
    if (i >= tot) return;
    float4 g = ((const float4*)o_gcn)[i];
    float4 sm = ((const float4*)o_sm)[i];
    float4 sx = ((const float4*)o_sx)[i];
    float4 gi = ((const float4*)o_gin)[i];
    float4 ga = ((const float4*)o_gat)[i];
    float w0 = scal[layer * 5 + 0], w1 = scal[layer * 5 + 1], w2 = scal[layer * 5 + 2];
    float w3 = scal[layer * 5 + 3], w4 = scal[layer * 5 + 4];
    float4 r;
    r.x = w0 * eluf(g.x) + w1 * eluf(sm.x) + w2 * eluf(sx.x) + w3 * eluf(gi.x) + w4 * eluf(ga.x);
    r.y = w0 * eluf(g.y) + w1 * eluf(sm.y) + w2 * eluf(sx.y) + w3 * eluf(gi.y) + w4 * eluf(ga.y);
    r.z = w0 * eluf(g.z) + w1 * eluf(sm.z) + w2 * eluf(sx.z) + w3 * eluf(gi.z) + w4 * eluf(ga.z);
    r.w = w0 * eluf(g.w) + w1 * eluf(sm.w) + w2 * eluf(sx.w) + w3 * eluf(gi.w) + w4 * eluf(ga.w);
    ((float4*)xo)[i] = r;
}

__global__ void maxmean_kernel(const float* __restrict__ x1, const float* __restrict__ x2,
                               const float* __restrict__ x3, const float* __restrict__ scal,
                               float* __restrict__ omax, float* __restrict__ omean, int tot4) {
    int i = blockIdx.x * blockDim.x + threadIdx.x;
    if (i >= tot4) return;
    float s1 = scal[15], s2 = scal[16];
    float4 a = ((const float4*)x3)[i];
    float4 b = ((const float4*)x1)[i];
    float4 c = ((const float4*)x2)[i];
    b.x *= s1; b.y *= s1; b.z *= s1; b.w *= s1;
    c.x *= s2; c.y *= s2; c.z *= s2; c.w *= s2;
    float4 mx, mn;
    mx.x = fmaxf(a.x, fmaxf(b.x, c.x)); mx.y = fmaxf(a.y, fmaxf(b.y, c.y));
    mx.z = fmaxf(a.z, fmaxf(b.z, c.z)); mx.w = fmaxf(a.w, fmaxf(b.w, c.w));
    const float third = 1.f / 3.f;
    mn.x = (a.x + b.x + c.x) * third; mn.y = (a.y + b.y + c.y) * third;
    mn.z = (a.z + b.z + c.z) * third; mn.w = (a.w + b.w + c.w) * third;
    ((float4*)omax)[i] = mx;
    ((float4*)omean)[i] = mn;
}

__global__ void la_comb_kernel(const float* __restrict__ o_max, const float* __restrict__ o_cat,
                               const float* __restrict__ o_mean, const float* __restrict__ scal,
                               float* __restrict__ x5, int tot4) {
    int i = blockIdx.x * blockDim.x + threadIdx.x;
    if (i >= tot4) return;
    float l0 = scal[17], l1 = scal[18], l2 = scal[19];
    float4 a = ((const float4*)o_max)[i];
    float4 b = ((const float4*)o_cat)[i];
    float4 c = ((const float4*)o_mean)[i];
    float4 r;
    r.x = l0 * a.x + l1 * b.x + l2 * c.x;
    r.y = l0 * a.y + l1 * b.y + l2 * c.y;
    r.z = l0 * a.z + l1 * b.z + l2 * c.z;
    r.w = l0 * a.w + l1 * b.w + l2 * c.w;
    ((float4*)x5)[i] = r;
}

// ---------------- launch ----------------
extern "C" void kernel_launch(void* const* d_in, const int* in_sizes, int n_in,
                              void* d_out, int out_size, void* d_ws, size_t ws_size,
                              hipStream_t stream) {
    const float* x = (const float*)d_in[0];
    const int* edge_index = (const int*)d_in[1];
    const float* lin1_w = (const float*)d_in[2];
    const float* lin1_b = (const float*)d_in[3];
    const float* gcn_w = (const float*)d_in[4];
    const float* sage_mean_w1 = (const float*)d_in[5];
    const float* sage_mean_w2 = (const float*)d_in[6];
    const float* sage_max_w1 = (const float*)d_in[7];
    const float* sage_max_w2 = (const float*)d_in[8];
    const float* gin_w = (const float*)d_in[9];
    const float* gat_w = (const float*)d_in[10];
    const float* gat_a = (const float*)d_in[11];
    const float* la_max_w = (const float*)d_in[12];
    const float* la_concat_w = (const float*)d_in[13];
    const float* la_mean_w = (const float*)d_in[14];
    const float* clf_w = (const float*)d_in[15];
    const float* clf_b = (const float*)d_in[16];
    const float* na_alphas = (const float*)d_in[17];
    const float* sc_alphas = (const float*)d_in[18];
    const float* la_alphas = (const float*)d_in[19];
    float* out = (float*)d_out;

    const int N = in_sizes[0] / IN_DIM_C;
    const int E = in_sizes[1] / 2;
    const int* src = edge_index;
    const int* dst = edge_index + E;

    // workspace layout
    char* base = (char*)d_ws;
    size_t off = 0;
    auto alloc = [&](size_t bytes) -> void* {
        void* p = base + off;
        off += (bytes + 255) & ~(size_t)255;
        return p;
    };
    const size_t NF = (size_t)N * HID * sizeof(float);
    float* S0 = (float*)alloc(NF);
    float* S1 = (float*)alloc(NF);
    float* S2 = (float*)alloc(NF);
    float* S3 = (float*)alloc(NF);
    float* AGs = (float*)alloc(NF);   // sm_in  -> o_sm
    float* AGg = (float*)alloc(NF);   // gcn_in -> o_gcn
    float* AGm = (float*)alloc(NF);   // ag_max -> o_sx
    float* AGa = (float*)alloc(NF);   // ag_gat -> o_gat
    float* TG  = (float*)alloc(NF);   // gin_in -> o_gin / o_cat
    int* csr_src = (int*)alloc((size_t)E * sizeof(int));
    int* cnt_i = (int*)alloc((size_t)2 * N * sizeof(int));  // cnt + cursor contiguous
    int* cursor = cnt_i + N;
    int* offs = (int*)alloc((size_t)N * sizeof(int));
    float* rsqd = (float*)alloc((size_t)N * sizeof(float));
    float* invcnt = (float*)alloc((size_t)N * sizeof(float));
    float* invdeg = (float*)alloc((size_t)N * sizeof(float));
    float* e_src_b = (float*)alloc((size_t)N * sizeof(float));
    float* e_dst_b = (float*)alloc((size_t)N * sizeof(float));
    float* va = (float*)alloc(6 * HID * sizeof(float));
    float* scal = (float*)alloc(64 * sizeof(float));

    const int NB_elem = (N * 32 + 255) / 256;     // float4 elementwise over N*128
    const int NB_gemm = (N + 63) / 64;
    const int NB_edge = (E + 255) / 256;
    const int NB_wave = (N + 3) / 4;              // 4 waves per 256-block
    const int NB_node = (N + 255) / 256;

    prep_kernel<<<1, 64, 0, stream>>>(na_alphas, sc_alphas, la_alphas, scal);
    gatvec_kernel<<<6, HID, 0, stream>>>(gat_w, gat_a, va);
    zero_int_kernel<<<(2 * N + 255) / 256, 256, 0, stream>>>(cnt_i, 2 * N);
    degree_kernel<<<NB_edge, 256, 0, stream>>>(dst, cnt_i, E);
    exscan_kernel<<<1, 1024, 0, stream>>>(cnt_i, offs, N);
    node_scalars_kernel<<<NB_node, 256, 0, stream>>>(cnt_i, rsqd, invcnt, invdeg, N);
    csr_fill_kernel<<<NB_edge, 256, 0, stream>>>(src, dst, offs, cursor, csr_src, E);

    // h0 = x @ lin1_w + lin1_b
    gemm_f32<<<NB_gemm, 256, 0, stream>>>(
        x, lin1_w, nullptr,
        nullptr, nullptr, nullptr,
        nullptr, nullptr, nullptr,
        lin1_b, S0, N, IN_DIM_C, HID, 0);

    const float* h = S0;
    float* xouts[3] = {S1, S2, S3};
    for (int i = 0; i < 3; ++i) {
        const float* Wg = gcn_w + (size_t)i * HID * HID;
        const float* Wa = gat_w + (size_t)i * HID * HID;
        const float* Wsm1 = sage_mean_w1 + (size_t)i * HID * HID;
        const float* Wsm2 = sage_mean_w2 + (size_t)i * HID * HID;
        const float* Wsx1 = sage_max_w1 + (size_t)i * HID * HID;
        const float* Wsx2 = sage_max_w2 + (size_t)i * HID * HID;
        const float* Wgin = gin_w + (size_t)i * HID * HID;
        float* xo = xouts[i];

        eproj_kernel<<<NB_wave, 256, 0, stream>>>(h, va, i, e_src_b, e_dst_b, N);
        aggregate_kernel<<<NB_wave, 256, 0, stream>>>(h, csr_src, e_src_b, e_dst_b,
                                                      offs, cnt_i,
                                                      rsqd, invcnt, invdeg,
                                                      AGs, AGg, TG, AGm, AGa, N);
        // all 5 layer GEMM products in one batched dispatch (independent slices)
        gemm_layer5<<<dim3(NB_gemm, 5), 256, 0, stream>>>(
            h, AGa, Wa, AGg, Wg, TG, Wgin, AGs, Wsm1, Wsm2, AGm, Wsx1, Wsx2, N);
        combine_kernel<<<NB_elem, 256, 0, stream>>>(AGg, AGs, AGm, TG, AGa, scal, i, xo, N);
        h = xo;
    }

    // Layer aggregation: inputs x1=S1, x2=S2, x3=S3
    maxmean_kernel<<<NB_elem, 256, 0, stream>>>(S1, S2, S3, scal, AGs, AGg, N * 32);
    // o_max = relu(max @ la_max_w)
    gemm_f32<<<NB_gemm, 256, 0, stream>>>(AGs, la_max_w, nullptr,
                                          nullptr, nullptr, nullptr,
                                          nullptr, nullptr, nullptr,
                                          nullptr, AGm, N, HID, HID, 1);
    // o_cat = relu(x3@W[0:128] + s1*x1@W[128:256] + s2*x2@W[256:384])
    gemm_f32<<<NB_gemm, 256, 0, stream>>>(S3, la_concat_w, nullptr,
                                          S1, la_concat_w + HID * HID, scal + 15,
                                          S2, la_concat_w + 2 * HID * HID, scal + 16,
                                          nullptr, TG, N, HID, HID, 1);
    // o_mean = relu(mean @ la_mean_w)  (in place over AGg)
    gemm_f32<<<NB_gemm, 256, 0, stream>>>(AGg, la_mean_w, nullptr,
                                          nullptr, nullptr, nullptr,
                                          nullptr, nullptr, nullptr,
                                          nullptr, AGg, N, HID, HID, 1);
    la_comb_kernel<<<NB_elem, 256, 0, stream>>>(AGm, TG, AGg, scal, AGs, N * 32);
    // out = x5 @ clf_w + clf_b
    gemm_f32<<<NB_gemm, 256, 0, stream>>>(AGs, clf_w, nullptr,
                                          nullptr, nullptr, nullptr,
                                          nullptr, nullptr, nullptr,
                                          clf_b, out, N, HID, 64, 0);
}

// Round 9
// 1551.675 us; speedup vs baseline: 1.0671x; 1.0671x over previous
//
#include <hip/hip_runtime.h>
#include <math.h>

#define HID 128
#define IN_DIM_C 500

typedef __attribute__((ext_vector_type(8))) short short8v;
typedef __attribute__((ext_vector_type(4))) short short4v;
typedef __attribute__((ext_vector_type(4))) float f32x4;

// ---------------- small helpers ----------------
__device__ inline float eluf(float x) { return x > 0.f ? x : expm1f(x); }

__device__ inline unsigned short f2bf(float x) {   // RTNE fp32 -> bf16
    unsigned u = __float_as_uint(x);
    u += 0x7fff + ((u >> 16) & 1);
    return (unsigned short)(u >> 16);
}
__device__ inline float bf2f(unsigned short h) {
    return __uint_as_float(((unsigned)h) << 16);
}

// ---------------- scalar prep (softmaxes of alphas) ----------------
__global__ void prep_kernel(const float* __restrict__ na, const float* __restrict__ sc,
                            const float* __restrict__ la, float* __restrict__ s) {
    if (threadIdx.x != 0 || blockIdx.x != 0) return;
    for (int i = 0; i < 3; ++i) {
        float m = -1e30f;
        for (int k = 0; k < 5; ++k) m = fmaxf(m, na[i * 5 + k]);
        float d = 0.f;
        for (int k = 0; k < 5; ++k) d += expf(na[i * 5 + k] - m);
        for (int k = 0; k < 5; ++k) s[i * 5 + k] = expf(na[i * 5 + k] - m) / d;
    }
    for (int i = 0; i < 2; ++i) {
        float a = sc[i * 2], b = sc[i * 2 + 1];
        float m = fmaxf(a, b);
        float e0 = expf(a - m), e1 = expf(b - m);
        s[15 + i] = e1 / (e0 + e1);   // weight of "skip"
    }
    {
        float m = fmaxf(la[0], fmaxf(la[1], la[2]));
        float d = 0.f;
        for (int k = 0; k < 3; ++k) d += expf(la[k] - m);
        for (int k = 0; k < 3; ++k) s[17 + k] = expf(la[k] - m) / d;
    }
}

// va[(layer*2+which)*HID + j] = dot(gat_w[layer] row j, gat_a[layer][which])
__global__ void gatvec_kernel(const float* __restrict__ gat_w, const float* __restrict__ gat_a,
                              float* __restrict__ va) {
    int b = blockIdx.x;              // 0..5
    int layer = b >> 1, which = b & 1;
    int j = threadIdx.x;             // 0..127
    const float* W = gat_w + ((size_t)layer * HID + j) * HID;
    const float* a = gat_a + (size_t)layer * 2 * HID + which * HID;
    float s = 0.f;
    for (int k = 0; k < HID; k += 4) {
        float4 w = *(const float4*)&W[k];
        float4 av = *(const float4*)&a[k];
        s += w.x * av.x + w.y * av.y + w.z * av.z + w.w * av.w;
    }
    va[b * HID + j] = s;
}

// ---------------- weight pre-pack: mfma B-fragment order, hi/lo bf16 split ----------
// matrix id m = op*3 + layer, op: 0=gat_w 1=gcn_w 2=gin_w 3=sm1 4=sm2 5=sx1 6=sx2
// frag element: B[k][n], k = kc*32 + 8*(l>>4) + j, n = ct*16 + (l&15), piece p = kc*8+ct
// dst index: ((m*2048 + p*64 + l)*8 + j)
__global__ void convw_kernel(const float* __restrict__ gat_w, const float* __restrict__ gcn_w,
                             const float* __restrict__ gin_w, const float* __restrict__ sm1,
                             const float* __restrict__ sm2, const float* __restrict__ sx1,
                             const float* __restrict__ sx2,
                             unsigned short* __restrict__ pk_hi,
                             unsigned short* __restrict__ pk_lo) {
    int tid = blockIdx.x * 256 + threadIdx.x;
    if (tid >= 21 * 32 * 64) return;
    int l = tid & 63;
    int p = (tid >> 6) & 31;
    int m = tid >> 11;               // 0..20
    int op = m / 3, layer = m % 3;
    const float* W;
    switch (op) {
        case 0: W = gat_w; break;
        case 1: W = gcn_w; break;
        case 2: W = gin_w; break;
        case 3: W = sm1; break;
        case 4: W = sm2; break;
        case 5: W = sx1; break;
        default: W = sx2; break;
    }
    W += (size_t)layer * HID * HID;
    int kc = p >> 3, ct = p & 7;
    int kbase = kc * 32 + 8 * (l >> 4);
    int col = ct * 16 + (l & 15);
    size_t dbase = ((size_t)m * 2048 + (size_t)p * 64 + l) * 8;
    for (int j = 0; j < 8; ++j) {
        float x = W[(size_t)(kbase + j) * HID + col];
        unsigned short h = f2bf(x);
        pk_hi[dbase + j] = h;
        pk_lo[dbase + j] = f2bf(x - bf2f(h));
    }
}

// ---------------- graph preprocessing ----------------
__global__ void zero_int_kernel(int* __restrict__ p, int n) {
    int i = blockIdx.x * blockDim.x + threadIdx.x;
    if (i < n) p[i] = 0;
}

__global__ void degree_kernel(const int* __restrict__ dst, int* __restrict__ cnt, int E) {
    int e = blockIdx.x * blockDim.x + threadIdx.x;
    if (e < E) atomicAdd(&cnt[dst[e]], 1);
}

// Blocked single-block exclusive scan.
__global__ __launch_bounds__(1024) void exscan_kernel(const int* __restrict__ in,
                                                      int* __restrict__ out, int n) {
    __shared__ int buf[1024];
    int t = threadIdx.x;
    int chunk = (n + 1023) >> 10;
    int base = t * chunk;
    int end = base + chunk;
    if (end > n) end = n;
    int s = 0;
    for (int i = base; i < end; ++i) s += in[i];
    buf[t] = s;
    __syncthreads();
    int x = s;
    for (int o = 1; o < 1024; o <<= 1) {
        int add = (t >= o) ? buf[t - o] : 0;
        __syncthreads();
        x += add;
        buf[t] = x;
        __syncthreads();
    }
    int running = x - s;   // exclusive offset of this thread's chunk
    for (int i = base; i < end; ++i) {
        out[i] = running;
        running += in[i];
    }
}

__global__ void node_scalars_kernel(const int* __restrict__ cnt, float* __restrict__ rsqd,
                                    float* __restrict__ invcnt, float* __restrict__ invdeg, int n) {
    int i = blockIdx.x * blockDim.x + threadIdx.x;
    if (i >= n) return;
    float c = (float)cnt[i];
    rsqd[i] = rsqrtf(c + 1.f);
    invcnt[i] = 1.f / fmaxf(c, 1.f);
    invdeg[i] = 1.f / (c + 1.f);
}

__global__ void csr_fill_kernel(const int* __restrict__ src, const int* __restrict__ dst,
                                const int* __restrict__ offs, int* __restrict__ cursor,
                                int* __restrict__ csr_src, int E) {
    int e = blockIdx.x * blockDim.x + threadIdx.x;
    if (e >= E) return;
    int d = dst[e];
    int pos = offs[d] + atomicAdd(&cursor[d], 1);
    csr_src[pos] = src[e];
}

// ---------------- fp32 GEMM (kept for lin1 + final stage) --------
__device__ __forceinline__ void gemm_body(
    const float* A1, const float* __restrict__ B1, const float* __restrict__ sc1p,
    const float* A2, const float* __restrict__ B2, const float* __restrict__ sc2p,
    const float* A3, const float* __restrict__ B3, const float* __restrict__ sc3p,
    const float* __restrict__ bias, float* C,
    int n, int K, int ncol, int act, int blk) {
    __shared__ float As[64][64];
    __shared__ float Bs[64][128];
    const int t = threadIdx.x;
    const int tx = t & 31, ty = t >> 5;
    const int rowbase = blk * 64;

    float4 acc[8];
#pragma unroll
    for (int r = 0; r < 8; ++r) { acc[r].x = 0.f; acc[r].y = 0.f; acc[r].z = 0.f; acc[r].w = 0.f; }

    const float* Aarr[3] = {A1, A2, A3};
    const float* Barr[3] = {B1, B2, B3};
    const float* scarr[3] = {sc1p, sc2p, sc3p};

    const int nf4 = ncol >> 2;

    for (int op = 0; op < 3; ++op) {
        const float* A = Aarr[op];
        if (!A) break;
        const float* B = Barr[op];
        float scv = scarr[op] ? *scarr[op] : 1.f;
        for (int k0 = 0; k0 < K; k0 += 64) {
            __syncthreads();
#pragma unroll
            for (int i = 0; i < 4; ++i) {
                int idx = t + i * 256;
                int row = idx >> 4, f4 = idx & 15;
                int grow = rowbase + row, gk = k0 + f4 * 4;
                float4 v; v.x = v.y = v.z = v.w = 0.f;
                if (grow < n) {
                    if (gk + 4 <= K) {
                        v = *(const float4*)&A[(size_t)grow * K + gk];
                    } else {
                        float tmp[4] = {0.f, 0.f, 0.f, 0.f};
                        for (int kk = 0; kk < 4; ++kk)
                            if (gk + kk < K) tmp[kk] = A[(size_t)grow * K + gk + kk];
                        v.x = tmp[0]; v.y = tmp[1]; v.z = tmp[2]; v.w = tmp[3];
                    }
                    v.x *= scv; v.y *= scv; v.z *= scv; v.w *= scv;
                }
                *(float4*)&As[row][f4 * 4] = v;
            }
            for (int idx = t; idx < 64 * nf4; idx += 256) {
                int kr = idx / nf4, c4 = idx % nf4;
                int gk = k0 + kr;
                float4 v; v.x = v.y = v.z = v.w = 0.f;
                if (gk < K) v = *(const float4*)&B[(size_t)gk * ncol + c4 * 4];
                *(float4*)&Bs[kr][c4 * 4] = v;
            }
            __syncthreads();
            if (tx * 4 < ncol) {
                for (int k = 0; k < 64; k += 4) {
                    float4 b0 = *(const float4*)&Bs[k][tx * 4];
                    float4 b1 = *(const float4*)&Bs[k + 1][tx * 4];
                    float4 b2 = *(const float4*)&Bs[k + 2][tx * 4];
                    float4 b3 = *(const float4*)&Bs[k + 3][tx * 4];
#pragma unroll
                    for (int r = 0; r < 8; ++r) {
                        float4 a = *(const float4*)&As[ty * 8 + r][k];
                        acc[r].x += a.x * b0.x + a.y * b1.x + a.z * b2.x + a.w * b3.x;
                        acc[r].y += a.x * b0.y + a.y * b1.y + a.z * b2.y + a.w * b3.y;
                        acc[r].z += a.x * b0.z + a.y * b1.z + a.z * b2.z + a.w * b3.z;
                        acc[r].w += a.x * b0.w + a.y * b1.w + a.z * b2.w + a.w * b3.w;
                    }
                }
            }
        }
    }

    if (tx * 4 < ncol) {
        float4 bv; bv.x = bv.y = bv.z = bv.w = 0.f;
        if (bias) bv = *(const float4*)&bias[tx * 4];
#pragma unroll
        for (int r = 0; r < 8; ++r) {
            int row = rowbase + ty * 8 + r;
            if (row >= n) break;
            float4 v = acc[r];
            v.x += bv.x; v.y += bv.y; v.z += bv.z; v.w += bv.w;
            if (act) {
                v.x = fmaxf(v.x, 0.f); v.y = fmaxf(v.y, 0.f);
                v.z = fmaxf(v.z, 0.f); v.w = fmaxf(v.w, 0.f);
            }
            *(float4*)&C[(size_t)row * ncol + tx * 4] = v;
        }
    }
}

__global__ __launch_bounds__(256) void gemm_f32(
    const float* A1, const float* __restrict__ B1, const float* __restrict__ sc1p,
    const float* A2, const float* __restrict__ B2, const float* __restrict__ sc2p,
    const float* A3, const float* __restrict__ B3, const float* __restrict__ sc3p,
    const float* __restrict__ bias, float* C,
    int n, int K, int ncol, int act) {
    gemm_body(A1, B1, sc1p, A2, B2, sc2p, A3, B3, sc3p, bias, C, n, K, ncol, act,
              blockIdx.x);
}

// ---------------- MFMA bf16-split batched layer GEMM ----------------
// 5 slices (blockIdx.y): 0: AGa@Wa->AGa  1: AGg@Wg->AGg  2: TG@Wgin->TG
//                        3: h@Wsm1 + AGs@Wsm2 -> AGs     4: h@Wsx1 + AGm@Wsx2 -> AGm
// Each block: 64 rows x 128 cols. 4 waves, wave w owns rows w*16..w*16+15.
// A staged fp32 -> hi/lo bf16 in XOR-swizzled LDS; B read pre-packed from pk_hi/pk_lo.
// Split product: A*B ~= Ah*Bh + Al*Bh + Ah*Bl (fp32 accumulate).
__global__ __launch_bounds__(256) void gemm5_mfma(
    const float* __restrict__ h,
    float* AGa, float* AGg, float* TG, float* AGs, float* AGm,
    const unsigned short* __restrict__ pk_hi, const unsigned short* __restrict__ pk_lo,
    int layer, int n) {
    __shared__ short Ah[64 * 128];
    __shared__ short Al[64 * 128];
    const int t = threadIdx.x;
    const int w = t >> 6, l = t & 63;
    const int rowbase = blockIdx.x * 64;

    const float* A1; const float* A2 = nullptr; float* C;
    int m1, m2 = -1;
    switch (blockIdx.y) {
        case 0: A1 = AGa; C = AGa; m1 = 0 + layer; break;
        case 1: A1 = AGg; C = AGg; m1 = 3 + layer; break;
        case 2: A1 = TG;  C = TG;  m1 = 6 + layer; break;
        case 3: A1 = h; A2 = AGs; C = AGs; m1 = 9 + layer;  m2 = 12 + layer; break;
        default: A1 = h; A2 = AGm; C = AGm; m1 = 15 + layer; m2 = 18 + layer; break;
    }

    f32x4 acc[8];
#pragma unroll
    for (int ct = 0; ct < 8; ++ct) { acc[ct][0] = 0.f; acc[ct][1] = 0.f; acc[ct][2] = 0.f; acc[ct][3] = 0.f; }

    for (int opi = 0; opi < 2; ++opi) {
        const float* A = opi ? A2 : A1;
        if (!A) break;
        int mm = opi ? m2 : m1;
        __syncthreads();
        // stage A: 64x128 fp32 -> hi/lo bf16 LDS (swizzled: byte ^= (row&7)<<4)
#pragma unroll
        for (int i = 0; i < 8; ++i) {
            int idx = t + i * 256;            // 0..2047 over 64 rows x 32 float4
            int row = idx >> 5;
            int kb = (idx & 31) * 4;          // k start (4 floats)
            int grow = rowbase + row;
            float4 v; v.x = v.y = v.z = v.w = 0.f;
            if (grow < n) v = *(const float4*)&A[(size_t)grow * HID + kb];
            unsigned short h0 = f2bf(v.x), h1 = f2bf(v.y), h2 = f2bf(v.z), h3 = f2bf(v.w);
            short4v hv; hv[0] = (short)h0; hv[1] = (short)h1; hv[2] = (short)h2; hv[3] = (short)h3;
            short4v lv;
            lv[0] = (short)f2bf(v.x - bf2f(h0));
            lv[1] = (short)f2bf(v.y - bf2f(h1));
            lv[2] = (short)f2bf(v.z - bf2f(h2));
            lv[3] = (short)f2bf(v.w - bf2f(h3));
            int boff = row * 256 + ((kb * 2) ^ ((row & 7) << 4));
            *(short4v*)((char*)Ah + boff) = hv;
            *(short4v*)((char*)Al + boff) = lv;
        }
        __syncthreads();
        // compute
        const unsigned short* bh = pk_hi + (size_t)mm * 16384;
        const unsigned short* bl = pk_lo + (size_t)mm * 16384;
        const int arow = (w << 4) + (l & 15);
        const int swz = (arow & 7) << 4;
        const int abase = arow * 256;
#pragma unroll
        for (int kc = 0; kc < 4; ++kc) {
            int k0 = kc * 32 + ((l >> 4) << 3);
            int boffA = abase + ((k0 * 2) ^ swz);
            short8v a_h = *(const short8v*)((const char*)Ah + boffA);
            short8v a_l = *(const short8v*)((const char*)Al + boffA);
#pragma unroll
            for (int ct = 0; ct < 8; ++ct) {
                size_t fo = (((size_t)(kc * 8 + ct)) * 64 + l) * 8;
                short8v b_h = *(const short8v*)&bh[fo];
                short8v b_l = *(const short8v*)&bl[fo];
                acc[ct] = __builtin_amdgcn_mfma_f32_16x16x32_bf16(a_h, b_h, acc[ct], 0, 0, 0);
                acc[ct] = __builtin_amdgcn_mfma_f32_16x16x32_bf16(a_l, b_h, acc[ct], 0, 0, 0);
                acc[ct] = __builtin_amdgcn_mfma_f32_16x16x32_bf16(a_h, b_l, acc[ct], 0, 0, 0);
            }
        }
    }

    // epilogue: D col = lane&15, row = 4*(lane>>4)+reg
    const int colb = l & 15;
    const int rgrp = (l >> 4) << 2;
#pragma unroll
    for (int ct = 0; ct < 8; ++ct) {
#pragma unroll
        for (int r = 0; r < 4; ++r) {
            int row = rowbase + (w << 4) + rgrp + r;
            if (row < n) C[(size_t)row * HID + ct * 16 + colb] = acc[ct][r];
        }
    }
}

// ---------------- GAT logits: es = h @ va0, ed = h @ va1 (wave per node) ----------------
__global__ __launch_bounds__(256) void eproj_kernel(const float* __restrict__ h,
                                                    const float* __restrict__ va, int layer,
                                                    float* __restrict__ es, float* __restrict__ ed,
                                                    int n) {
    int wid = (blockIdx.x * 256 + threadIdx.x) >> 6;
    int lane = threadIdx.x & 63;
    if (wid >= n) return;
    float2 v = *(const float2*)&h[(size_t)wid * HID + lane * 2];
    float2 w0 = *(const float2*)&va[(layer * 2 + 0) * HID + lane * 2];
    float2 w1 = *(const float2*)&va[(layer * 2 + 1) * HID + lane * 2];
    float s0 = v.x * w0.x + v.y * w0.y;
    float s1 = v.x * w1.x + v.y * w1.y;
#pragma unroll
    for (int o = 32; o > 0; o >>= 1) {
        s0 += __shfl_xor(s0, o);
        s1 += __shfl_xor(s1, o);
    }
    if (lane == 0) { es[wid] = s0; ed[wid] = s1; }
}

// ---------------- fused per-node aggregation over h only (wave per node) ----------------
__global__ __launch_bounds__(256) void aggregate_kernel(
    const float* __restrict__ h, const int* __restrict__ csr_src,
    const float* __restrict__ es, const float* __restrict__ ed,
    const int* __restrict__ offs, const int* __restrict__ cnt,
    const float* __restrict__ rsqd, const float* __restrict__ invcnt,
    const float* __restrict__ invdeg,
    float* __restrict__ sm_in, float* __restrict__ gcn_in, float* __restrict__ gin_in,
    float* __restrict__ ag_max, float* __restrict__ ag_gat, int n) {
    int wid = (blockIdx.x * 256 + threadIdx.x) >> 6;
    int lane = threadIdx.x & 63;
    if (wid >= n) return;
    int beg = offs[wid];
    int m = cnt[wid];
    int end = beg + m;
    float edv = ed[wid];

    float emax = -INFINITY;
    for (int j = beg + lane; j < end; j += 64) {
        float v = es[csr_src[j]] + edv;
        float e = v > 0.f ? v : 0.2f * v;
        emax = fmaxf(emax, e);
    }
#pragma unroll
    for (int o = 32; o > 0; o >>= 1) emax = fmaxf(emax, __shfl_xor(emax, o));
    float den = 0.f;
    for (int j = beg + lane; j < end; j += 64) {
        float v = es[csr_src[j]] + edv;
        float e = v > 0.f ? v : 0.2f * v;
        den += __expf(e - emax);
    }
#pragma unroll
    for (int o = 32; o > 0; o >>= 1) den += __shfl_xor(den, o);
    float inv_den = 1.f / (den + 1e-16f);

    const float2* h2 = (const float2*)h;
    float sx = 0.f, sy = 0.f, gx = 0.f, gy = 0.f, ax = 0.f, ay = 0.f;
    float mxx = -INFINITY, mxy = -INFINITY;
#pragma unroll 4
    for (int j = beg; j < end; ++j) {
        int s = csr_src[j];
        float v = es[s] + edv;
        float e = v > 0.f ? v : 0.2f * v;
        float coef = __expf(e - emax) * inv_den;
        float rsd = rsqd[s];
        float2 hv = h2[(size_t)s * 64 + lane];
        sx += hv.x; sy += hv.y;
        gx += rsd * hv.x; gy += rsd * hv.y;
        mxx = fmaxf(mxx, hv.x); mxy = fmaxf(mxy, hv.y);
        ax += coef * hv.x; ay += coef * hv.y;
    }
    if (m == 0) { mxx = 0.f; mxy = 0.f; }

    size_t o2 = (size_t)wid * 64 + lane;
    float2 hd = h2[o2];
    float icnt = invcnt[wid];
    float idg = invdeg[wid];
    float rsd_d = rsqd[wid];
    float2 r;
    r.x = icnt * sx;             r.y = icnt * sy;             ((float2*)sm_in)[o2] = r;
    r.x = idg * hd.x + rsd_d * gx; r.y = idg * hd.y + rsd_d * gy; ((float2*)gcn_in)[o2] = r;
    r.x = hd.x + sx;             r.y = hd.y + sy;             ((float2*)gin_in)[o2] = r;
    r.x = mxx;                   r.y = mxy;                   ((float2*)ag_max)[o2] = r;
    r.x = ax;                    r.y = ay;                    ((float2*)ag_gat)[o2] = r;
}

// ---------------- elementwise kernels ----------------
__global__ void combine_kernel(const float* __restrict__ o_gcn, const float* __restrict__ o_sm,
                               const float* __restrict__ o_sx, const float* __restrict__ o_gin,
                               const float* __restrict__ o_gat,
                               const float* __restrict__ scal, int layer,
                               float* __restrict__ xo, int n) {
    int i = blockIdx.x * blockDim.x + threadIdx.x;
    int tot = n * 32;
    if (i >= tot) return;
    float4 g = ((const float4*)o_gcn)[i];
    float4 sm = ((const float4*)o_sm)[i];
    float4 sx = ((const float4*)o_sx)[i];
    float4 gi = ((const float4*)o_gin)[i];
    float4 ga = ((const float4*)o_gat)[i];
    float w0 = scal[layer * 5 + 0], w1 = scal[layer * 5 + 1], w2 = scal[layer * 5 + 2];
    float w3 = scal[layer * 5 + 3], w4 = scal[layer * 5 + 4];
    float4 r;
    r.x = w0 * eluf(g.x) + w1 * eluf(sm.x) + w2 * eluf(sx.x) + w3 * eluf(gi.x) + w4 * eluf(ga.x);
    r.y = w0 * eluf(g.y) + w1 * eluf(sm.y) + w2 * eluf(sx.y) + w3 * eluf(gi.y) + w4 * eluf(ga.y);
    r.z = w0 * eluf(g.z) + w1 * eluf(sm.z) + w2 * eluf(sx.z) + w3 * eluf(gi.z) + w4 * eluf(ga.z);
    r.w = w0 * eluf(g.w) + w1 * eluf(sm.w) + w2 * eluf(sx.w) + w3 * eluf(gi.w) + w4 * eluf(ga.w);
    ((float4*)xo)[i] = r;
}

__global__ void maxmean_kernel(const float* __restrict__ x1, const float* __restrict__ x2,
                               const float* __restrict__ x3, const float* __restrict__ scal,
                               float* __restrict__ omax, float* __restrict__ omean, int tot4) {
    int i = blockIdx.x * blockDim.x + threadIdx.x;
    if (i >= tot4) return;
    float s1 = scal[15], s2 = scal[16];
    float4 a = ((const float4*)x3)[i];
    float4 b = ((const float4*)x1)[i];
    float4 c = ((const float4*)x2)[i];
    b.x *= s1; b.y *= s1; b.z *= s1; b.w *= s1;
    c.x *= s2; c.y *= s2; c.z *= s2; c.w *= s2;
    float4 mx, mn;
    mx.x = fmaxf(a.x, fmaxf(b.x, c.x)); mx.y = fmaxf(a.y, fmaxf(b.y, c.y));
    mx.z = fmaxf(a.z, fmaxf(b.z, c.z)); mx.w = fmaxf(a.w, fmaxf(b.w, c.w));
    const float third = 1.f / 3.f;
    mn.x = (a.x + b.x + c.x) * third; mn.y = (a.y + b.y + c.y) * third;
    mn.z = (a.z + b.z + c.z) * third; mn.w = (a.w + b.w + c.w) * third;
    ((float4*)omax)[i] = mx;
    ((float4*)omean)[i] = mn;
}

__global__ void la_comb_kernel(const float* __restrict__ o_max, const float* __restrict__ o_cat,
                               const float* __restrict__ o_mean, const float* __restrict__ scal,
                               float* __restrict__ x5, int tot4) {
    int i = blockIdx.x * blockDim.x + threadIdx.x;
    if (i >= tot4) return;
    float l0 = scal[17], l1 = scal[18], l2 = scal[19];
    float4 a = ((const float4*)o_max)[i];
    float4 b = ((const float4*)o_cat)[i];
    float4 c = ((const float4*)o_mean)[i];
    float4 r;
    r.x = l0 * a.x + l1 * b.x + l2 * c.x;
    r.y = l0 * a.y + l1 * b.y + l2 * c.y;
    r.z = l0 * a.z + l1 * b.z + l2 * c.z;
    r.w = l0 * a.w + l1 * b.w + l2 * c.w;
    ((float4*)x5)[i] = r;
}

// ---------------- launch ----------------
extern "C" void kernel_launch(void* const* d_in, const int* in_sizes, int n_in,
                              void* d_out, int out_size, void* d_ws, size_t ws_size,
                              hipStream_t stream) {
    const float* x = (const float*)d_in[0];
    const int* edge_index = (const int*)d_in[1];
    const float* lin1_w = (const float*)d_in[2];
    const float* lin1_b = (const float*)d_in[3];
    const float* gcn_w = (const float*)d_in[4];
    const float* sage_mean_w1 = (const float*)d_in[5];
    const float* sage_mean_w2 = (const float*)d_in[6];
    const float* sage_max_w1 = (const float*)d_in[7];
    const float* sage_max_w2 = (const float*)d_in[8];
    const float* gin_w = (const float*)d_in[9];
    const float* gat_w = (const float*)d_in[10];
    const float* gat_a = (const float*)d_in[11];
    const float* la_max_w = (const float*)d_in[12];
    const float* la_concat_w = (const float*)d_in[13];
    const float* la_mean_w = (const float*)d_in[14];
    const float* clf_w = (const float*)d_in[15];
    const float* clf_b = (const float*)d_in[16];
    const float* na_alphas = (const float*)d_in[17];
    const float* sc_alphas = (const float*)d_in[18];
    const float* la_alphas = (const float*)d_in[19];
    float* out = (float*)d_out;

    const int N = in_sizes[0] / IN_DIM_C;
    const int E = in_sizes[1] / 2;
    const int* src = edge_index;
    const int* dst = edge_index + E;

    // workspace layout
    char* base = (char*)d_ws;
    size_t off = 0;
    auto alloc = [&](size_t bytes) -> void* {
        void* p = base + off;
        off += (bytes + 255) & ~(size_t)255;
        return p;
    };
    const size_t NF = (size_t)N * HID * sizeof(float);
    float* S0 = (float*)alloc(NF);
    float* S1 = (float*)alloc(NF);
    float* S2 = (float*)alloc(NF);
    float* S3 = (float*)alloc(NF);
    float* AGs = (float*)alloc(NF);   // sm_in  -> o_sm
    float* AGg = (float*)alloc(NF);   // gcn_in -> o_gcn
    float* AGm = (float*)alloc(NF);   // ag_max -> o_sx
    float* AGa = (float*)alloc(NF);   // ag_gat -> o_gat
    float* TG  = (float*)alloc(NF);   // gin_in -> o_gin / o_cat
    int* csr_src = (int*)alloc((size_t)E * sizeof(int));
    int* cnt_i = (int*)alloc((size_t)2 * N * sizeof(int));  // cnt + cursor contiguous
    int* cursor = cnt_i + N;
    int* offs = (int*)alloc((size_t)N * sizeof(int));
    float* rsqd = (float*)alloc((size_t)N * sizeof(float));
    float* invcnt = (float*)alloc((size_t)N * sizeof(float));
    float* invdeg = (float*)alloc((size_t)N * sizeof(float));
    float* e_src_b = (float*)alloc((size_t)N * sizeof(float));
    float* e_dst_b = (float*)alloc((size_t)N * sizeof(float));
    float* va = (float*)alloc(6 * HID * sizeof(float));
    float* scal = (float*)alloc(64 * sizeof(float));
    unsigned short* pk_hi = (unsigned short*)alloc((size_t)21 * 16384 * sizeof(unsigned short));
    unsigned short* pk_lo = (unsigned short*)alloc((size_t)21 * 16384 * sizeof(unsigned short));

    const int NB_elem = (N * 32 + 255) / 256;     // float4 elementwise over N*128
    const int NB_gemm = (N + 63) / 64;
    const int NB_edge = (E + 255) / 256;
    const int NB_wave = (N + 3) / 4;              // 4 waves per 256-block
    const int NB_node = (N + 255) / 256;

    prep_kernel<<<1, 64, 0, stream>>>(na_alphas, sc_alphas, la_alphas, scal);
    gatvec_kernel<<<6, HID, 0, stream>>>(gat_w, gat_a, va);
    convw_kernel<<<(21 * 32 * 64 + 255) / 256, 256, 0, stream>>>(
        gat_w, gcn_w, gin_w, sage_mean_w1, sage_mean_w2, sage_max_w1, sage_max_w2,
        pk_hi, pk_lo);
    zero_int_kernel<<<(2 * N + 255) / 256, 256, 0, stream>>>(cnt_i, 2 * N);
    degree_kernel<<<NB_edge, 256, 0, stream>>>(dst, cnt_i, E);
    exscan_kernel<<<1, 1024, 0, stream>>>(cnt_i, offs, N);
    node_scalars_kernel<<<NB_node, 256, 0, stream>>>(cnt_i, rsqd, invcnt, invdeg, N);
    csr_fill_kernel<<<NB_edge, 256, 0, stream>>>(src, dst, offs, cursor, csr_src, E);

    // h0 = x @ lin1_w + lin1_b
    gemm_f32<<<NB_gemm, 256, 0, stream>>>(
        x, lin1_w, nullptr,
        nullptr, nullptr, nullptr,
        nullptr, nullptr, nullptr,
        lin1_b, S0, N, IN_DIM_C, HID, 0);

    const float* h = S0;
    float* xouts[3] = {S1, S2, S3};
    for (int i = 0; i < 3; ++i) {
        float* xo = xouts[i];
        eproj_kernel<<<NB_wave, 256, 0, stream>>>(h, va, i, e_src_b, e_dst_b, N);
        aggregate_kernel<<<NB_wave, 256, 0, stream>>>(h, csr_src, e_src_b, e_dst_b,
                                                      offs, cnt_i,
                                                      rsqd, invcnt, invdeg,
                                                      AGs, AGg, TG, AGm, AGa, N);
        // all 5 layer GEMM products in one batched MFMA dispatch
        gemm5_mfma<<<dim3(NB_gemm, 5), 256, 0, stream>>>(
            h, AGa, AGg, TG, AGs, AGm, pk_hi, pk_lo, i, N);
        combine_kernel<<<NB_elem, 256, 0, stream>>>(AGg, AGs, AGm, TG, AGa, scal, i, xo, N);
        h = xo;
    }

    // Layer aggregation: inputs x1=S1, x2=S2, x3=S3
    maxmean_kernel<<<NB_elem, 256, 0, stream>>>(S1, S2, S3, scal, AGs, AGg, N * 32);
    // o_max = relu(max @ la_max_w)
    gemm_f32<<<NB_gemm, 256, 0, stream>>>(AGs, la_max_w, nullptr,
                                          nullptr, nullptr, nullptr,
                                          nullptr, nullptr, nullptr,
                                          nullptr, AGm, N, HID, HID, 1);
    // o_cat = relu(x3@W[0:128] + s1*x1@W[128:256] + s2*x2@W[256:384])
    gemm_f32<<<NB_gemm, 256, 0, stream>>>(S3, la_concat_w, nullptr,
                                          S1, la_concat_w + HID * HID, scal + 15,
                                          S2, la_concat_w + 2 * HID * HID, scal + 16,
                                          nullptr, TG, N, HID, HID, 1);
    // o_mean = relu(mean @ la_mean_w)  (in place over AGg)
    gemm_f32<<<NB_gemm, 256, 0, stream>>>(AGg, la_mean_w, nullptr,
                                          nullptr, nullptr, nullptr,
                                          nullptr, nullptr, nullptr,
                                          nullptr, AGg, N, HID, HID, 1);
    la_comb_kernel<<<NB_elem, 256, 0, stream>>>(AGm, TG, AGg, scal, AGs, N * 32);
    // out = x5 @ clf_w + clf_b
    gemm_f32<<<NB_gemm, 256, 0, stream>>>(AGs, clf_w, nullptr,
                                          nullptr, nullptr, nullptr,
                                          nullptr, nullptr, nullptr,
                                          clf_b, out, N, HID, 64, 0);
}